// Round 4
// baseline (129.201 us; speedup 1.0000x reference)
//
#include <hip/hip_runtime.h>
#include <hip/hip_bf16.h>
#include <math.h>

// ---------------------------------------------------------------------------
// SAContrastiveAdversarialLoss on MI355X (gfx950)
// B=8192, D=128, S=64. Output: scalar fp32.
//
// loss = sum_i -log(1e-12 + num_i/denom_i) / (B*(2B-1))
//        + sum_i -log(1e-12 + 1 - picked_i)
//
// v5 structure:
//  - NOTE: the harness re-poisons the 256MiB workspace with a ~43us fill
//    INSIDE the timed region (r3 profile: fillBufferAligned 43us, 256MiB).
//    That is the floor; our kernels sit on top of it.
//  - prep: 16 rows/block (1024 thr); rows normalized into padded LDS
//    (272B stride), then 768 threads emit the fragment-tiled A/K2/K1 groups
//    as contiguous 16B-coalesced stores (kills the 4B-scatter store path).
//  - main: 256 rows x 512 cols/block; phases of 2 tiles (8KB), 4 LDS bufs,
//    3-deep prefetch with counted s_waitcnt vmcnt(4) (never 0 in loop),
//    ONE barrier per phase. T2 plain stores (no atomics).
//  - final_adv: 2048 blocks, one row/wave; block partial -> plain store;
//    sa_reduce (1 block) sums 2048 partials -> out.
// ---------------------------------------------------------------------------

#define NROWS 8192
#define DFEAT 128

typedef __bf16 bf16_t;
typedef __bf16 bf16x8 __attribute__((ext_vector_type(8)));
typedef __bf16 bf16x2 __attribute__((ext_vector_type(2)));
typedef float  f32x4  __attribute__((ext_vector_type(4)));

__device__ __forceinline__ float fexp2(float x) {
#if __has_builtin(__builtin_amdgcn_exp2f)
  return __builtin_amdgcn_exp2f(x);
#else
  return exp2f(x);
#endif
}

// async global->LDS, 16B per lane. gsrc is per-lane (includes +lane*16);
// lds dst is wave-uniform base (HW adds lane*16).
__device__ __forceinline__ void stage16(const void* gsrc, void* ldst) {
  __builtin_amdgcn_global_load_lds(
      (const __attribute__((address_space(1))) unsigned int*)gsrc,
      (__attribute__((address_space(3))) unsigned int*)ldst, 16, 0, 0);
}

#define WAITVM(n) asm volatile("s_waitcnt vmcnt(" #n ")" ::: "memory")

// ---------------------------------------------------------------------------
// prep: block = 16 rows = one fragment-tile group. Wave w normalizes row w
// into padded LDS (stride 136 bf16 = 272B -> dword-stride 68, bank-stride 4,
// <=2-way conflicts on the b128 readback). Then threads 0..767 write the
// A / K2 / K1 fragment-tile groups as contiguous coalesced 16B stores:
//   out[tile*2048 + u*8 + j] = L[u&15][(u>>6)*32 + ((u>>4)&3)*8 + j]
// which matches the main kernel's fragment layout
//   elem((tile*4+kf)*512 + (qk*16+row)*8 + j) = row value at k=kf*32+qk*8+j.
__global__ __launch_bounds__(1024)
void sa_prep_kernel(const float* __restrict__ z1,
                    const float* __restrict__ z2,
                    bf16_t* __restrict__ Abuf,
                    bf16_t* __restrict__ Kc,
                    float* __restrict__ numv,
                    float* __restrict__ d11v) {
  __shared__ __align__(16) bf16_t LA[16][136];
  __shared__ __align__(16) bf16_t LK2[16][136];
  __shared__ __align__(16) bf16_t LK1[16][136];

  int wave = threadIdx.x >> 6;   // 0..15 : row within tile
  int lane = threadIdx.x & 63;
  int tile = blockIdx.x;         // 0..511
  int row  = tile * 16 + wave;

  float2 a = ((const float2*)(z1 + (size_t)row * DFEAT))[lane];
  float2 b = ((const float2*)(z2 + (size_t)row * DFEAT))[lane];

  float s1  = a.x * a.x + a.y * a.y;
  float s2  = b.x * b.x + b.y * b.y;
  float s12 = a.x * b.x + a.y * b.y;
#pragma unroll
  for (int m = 32; m; m >>= 1) {
    s1  += __shfl_xor(s1, m, 64);
    s2  += __shfl_xor(s2, m, 64);
    s12 += __shfl_xor(s12, m, 64);
  }
  float r1 = 1.0f / fmaxf(sqrtf(s1), 1e-8f);  // COS_EPS
  float r2 = 1.0f / fmaxf(sqrtf(s2), 1e-8f);

  const float SCL = 14.426950408889634f;  // 10 * log2(e), folds /tau + exp2

  bf16x2 av;  av[0] = (bf16_t)(a.x * r1 * SCL); av[1] = (bf16_t)(a.y * r1 * SCL);
  bf16x2 k2v; k2v[0] = (bf16_t)(b.x * r2);      k2v[1] = (bf16_t)(b.y * r2);
  bf16x2 k1v; k1v[0] = (bf16_t)(a.x * r1);      k1v[1] = (bf16_t)(a.y * r1);

  *(bf16x2*)&LA[wave][2 * lane]  = av;
  *(bf16x2*)&LK2[wave][2 * lane] = k2v;
  *(bf16x2*)&LK1[wave][2 * lane] = k1v;

  if (lane == 0) {
    numv[row] = expf(10.0f * s12 * r1 * r2);
    d11v[row] = expf(10.0f * s1 * r1 * r1);
  }
  __syncthreads();

  int t = threadIdx.x;
  if (t < 768) {
    int sel = t >> 8;          // 0=A, 1=K2, 2=K1
    int u   = t & 255;
    int kf  = u >> 6;
    int qk  = (u >> 4) & 3;
    int r16 = u & 15;
    const bf16_t* Ls = (sel == 0) ? &LA[0][0]
                     : (sel == 1) ? &LK2[0][0] : &LK1[0][0];
    bf16x8 v = *(const bf16x8*)(Ls + r16 * 136 + kf * 32 + qk * 8);
    bf16_t* dst = (sel == 0) ? (Abuf + (size_t)tile * 2048)
                : (sel == 1) ? (Kc + (size_t)tile * 2048)
                             : (Kc + (size_t)(512 + tile) * 2048);
    *(bf16x8*)(dst + u * 8) = v;
  }
}

// ---------------------------------------------------------------------------
// main: fused "row-sum of exp(sim)" over the virtual 8192x16384 matrix.
// Block = 256 rows x 512 cols; wave w owns rows [bx*256 + w*64, +64).
// Phase = 2 tiles (32 cols, 8KB of Kc), 16 phases. Each wave stages 2KB
// (2 x global_load_lds_dwordx4) per phase; 4 LDS buffers; 3 phases in
// flight; steady-state wait = vmcnt(4) (own oldest 2 loads = this phase);
// ONE s_barrier per phase. Per phase: 32 MFMA + 32 exp2 per wave.
// MFMA C/D layout: col=lane&15, row=(lane>>4)*4+reg.
// Partial row-sums (512 cols) -> T2[row][by] as plain stores (no atomics).
__global__ __launch_bounds__(256, 4)
void sa_main_kernel(const bf16_t* __restrict__ Abuf,
                    const bf16_t* __restrict__ Kc,
                    float* __restrict__ T2) {
  __shared__ __align__(16) bf16_t bsm[4][4096];  // 4 x 8KB phase buffers

  int wave = threadIdx.x >> 6;
  int lane = threadIdx.x & 63;
  int quad = lane >> 4;

  // bijective XCD swizzle: 1024 blocks, 8 XCDs, 128 each. Each XCD sweeps
  // 4 col-chunks (512KB of Kc) + all of A (2MB) -> L2-resident.
  int id  = blockIdx.x;
  int swz = (id & 7) * 128 + (id >> 3);
  int bx  = swz & 31;   // row-block: 256 rows
  int by  = swz >> 5;   // col-chunk: 512 cols
  int rowBase = bx * 256 + wave * 64;
  int colBase = by * 512;

  // A fragments for this wave's 4 row-strips (fragment-tiled: consecutive
  // 1KB fragments, fully coalesced 16B/lane).
  const bf16x8* ap = (const bf16x8*)Abuf + (size_t)(rowBase >> 4) * 256 + lane;
  bf16x8 afrag[4][4];
#pragma unroll
  for (int s = 0; s < 4; ++s)
#pragma unroll
    for (int kfi = 0; kfi < 4; ++kfi)
      afrag[s][kfi] = ap[(s * 4 + kfi) * 64];

  f32x4 sums[4];
#pragma unroll
  for (int s = 0; s < 4; ++s) sums[s] = (f32x4){0.f, 0.f, 0.f, 0.f};

  // B stage source: phase p = 8KB at chunk-byte-base + p*8192.
  // Wave w stages 2KB: +w*2048 (+1024 for the second load), +lane*16.
  const char* bsrc = (const char*)Kc + (size_t)(colBase >> 4) * 4096 +
                     (size_t)wave * 2048 + (size_t)lane * 16;
  char* lbase = (char*)&bsm[0][0] + (size_t)wave * 2048;

  auto stagePhase = [&](int p) {
    const char* src = bsrc + (size_t)p * 8192;
    char* dst = lbase + (size_t)(p & 3) * 8192;
    stage16(src, dst);
    stage16(src + 1024, dst + 1024);
  };

  auto computePhase = [&](int pbuf) {
    const bf16_t* base = &bsm[0][0] + pbuf * 4096;
#pragma unroll
    for (int tt = 0; tt < 2; ++tt) {
      const bf16x8* bs = (const bf16x8*)(base + tt * 2048);
      bf16x8 bfr[4];
#pragma unroll
      for (int kfi = 0; kfi < 4; ++kfi) bfr[kfi] = bs[kfi * 64 + lane];
      __builtin_amdgcn_s_setprio(1);
#pragma unroll
      for (int s = 0; s < 4; ++s) {
        f32x4 c = {0.f, 0.f, 0.f, 0.f};
#pragma unroll
        for (int kfi = 0; kfi < 4; ++kfi)
          c = __builtin_amdgcn_mfma_f32_16x16x32_bf16(afrag[s][kfi], bfr[kfi],
                                                      c, 0, 0, 0);
#pragma unroll
        for (int r = 0; r < 4; ++r) sums[s][r] += fexp2(c[r]);
      }
      __builtin_amdgcn_s_setprio(0);
    }
  };

  // prologue: 3 phases in flight (6 loads/wave).
  stagePhase(0);
  stagePhase(1);
  stagePhase(2);

  // steady state: wait own oldest 2 loads (phase p) -> barrier -> issue
  // stage(p+3) early -> compute(p). Never drains to 0.
#pragma unroll 1
  for (int p = 0; p < 13; ++p) {
    WAITVM(4);
    __builtin_amdgcn_s_barrier();
    __builtin_amdgcn_sched_barrier(0);
    stagePhase(p + 3);
    computePhase(p & 3);
  }
  // epilogue: drain 4 -> 2 -> 0.
  WAITVM(4);
  __builtin_amdgcn_s_barrier();
  __builtin_amdgcn_sched_barrier(0);
  computePhase(1);  // p=13
  WAITVM(2);
  __builtin_amdgcn_s_barrier();
  __builtin_amdgcn_sched_barrier(0);
  computePhase(2);  // p=14
  WAITVM(0);
  __builtin_amdgcn_s_barrier();
  __builtin_amdgcn_sched_barrier(0);
  computePhase(3);  // p=15

  // Reduce across the 16 lanes of each quad-group (cols), then one lane
  // per quad commits 4 row partial-sums with plain stores (no atomics).
  int l15 = lane & 15;
#pragma unroll
  for (int s = 0; s < 4; ++s) {
#pragma unroll
    for (int r = 0; r < 4; ++r) {
      float v = sums[s][r];
      v += __shfl_xor(v, 1, 64);
      v += __shfl_xor(v, 2, 64);
      v += __shfl_xor(v, 4, 64);
      v += __shfl_xor(v, 8, 64);
      if (l15 == 0)
        T2[(size_t)(rowBase + s * 16 + quad * 4 + r) * 32 + by] = v;
    }
  }
}

// ---------------------------------------------------------------------------
// final+adv fused: 2048 blocks x 256 threads, one row per wave, fully
// parallel. Reduces the 32 T2 partials per row inside the same 64-lane
// butterfly as the adversarial argmax. Block partial -> plain store.
__global__ __launch_bounds__(256)
void sa_final_adv_kernel(const float* __restrict__ T2,
                         const float* __restrict__ numv,
                         const float* __restrict__ d11v,
                         const float* __restrict__ c,
                         const float* __restrict__ lab,
                         float* __restrict__ partial) {
  int wave = threadIdx.x >> 6;
  int lane = threadIdx.x & 63;
  int row  = blockIdx.x * 4 + wave;

  float cv = c[row * 64 + lane];
  float lv = lab[row * 64 + lane];
  float tv = (lane < 32) ? T2[(size_t)row * 32 + lane] : 0.0f;

  float ss = cv * cv;
  float bestv = lv;
  int   besti = lane;
#pragma unroll
  for (int m = 32; m; m >>= 1) {
    ss += __shfl_xor(ss, m, 64);
    tv += __shfl_xor(tv, m, 64);
    float ov = __shfl_xor(bestv, m, 64);
    int   oi = __shfl_xor(besti, m, 64);
    if (ov > bestv || (ov == bestv && oi < besti)) { bestv = ov; besti = oi; }
  }
  float picked = __shfl(cv, besti, 64) / fmaxf(sqrtf(ss), 1e-12f);

  float term = 0.0f;
  if (lane == 0) {
    float denom = tv - d11v[row];  // tv = full row sum of both exp blocks
    term = -logf(1e-12f + numv[row] / denom) * (1.0f / 134209536.0f)
           - logf(1e-12f + 1.0f - picked);  // LAM = 1
  }

  __shared__ float wacc[4];
  if (lane == 0) wacc[wave] = term;
  __syncthreads();
  if (threadIdx.x == 0)
    partial[blockIdx.x] = wacc[0] + wacc[1] + wacc[2] + wacc[3];
}

// ---------------------------------------------------------------------------
// reduce: single block sums the 2048 block partials -> out (plain store).
__global__ __launch_bounds__(256)
void sa_reduce_kernel(const float* __restrict__ partial,
                      float* __restrict__ out) {
  float v = 0.0f;
#pragma unroll
  for (int i = 0; i < 8; ++i) v += partial[threadIdx.x + 256 * i];
#pragma unroll
  for (int m = 32; m; m >>= 1) v += __shfl_xor(v, m, 64);
  __shared__ float wacc[4];
  if ((threadIdx.x & 63) == 0) wacc[threadIdx.x >> 6] = v;
  __syncthreads();
  if (threadIdx.x == 0) out[0] = wacc[0] + wacc[1] + wacc[2] + wacc[3];
}

// ---------------------------------------------------------------------------
extern "C" void kernel_launch(void* const* d_in, const int* in_sizes, int n_in,
                              void* d_out, int out_size, void* d_ws,
                              size_t ws_size, hipStream_t stream) {
  const float* z1  = (const float*)d_in[0];  // [8192,128]
  const float* z2  = (const float*)d_in[1];  // [8192,128]
  const float* co  = (const float*)d_in[2];  // [8192,64]
  const float* lab = (const float*)d_in[3];  // [8192,64]
  float* out = (float*)d_out;

  char* ws = (char*)d_ws;
  bf16_t* Abuf  = (bf16_t*)ws;                           // 8192*128*2 = 2 MB
  bf16_t* Kc    = (bf16_t*)(ws + 2u * 1024 * 1024);      // 16384*128*2 = 4 MB
  float*  T2    = (float*)(ws + 6u * 1024 * 1024);       // 8192*32*4 = 1 MB
  float*  numv  = (float*)(ws + 7u * 1024 * 1024);       // 32 KB
  float*  d11v  = numv + NROWS;                          // 32 KB
  float*  part  = d11v + NROWS;                          // 8 KB

  sa_prep_kernel<<<NROWS / 16, 1024, 0, stream>>>(z1, z2, Abuf, Kc, numv,
                                                  d11v);
  sa_main_kernel<<<1024, 256, 0, stream>>>(Abuf, Kc, T2);
  sa_final_adv_kernel<<<NROWS / 4, 256, 0, stream>>>(T2, numv, d11v, co, lab,
                                                     part);
  sa_reduce_kernel<<<1, 256, 0, stream>>>(part, out);
}